// Round 7
// baseline (519.297 us; speedup 1.0000x reference)
//
#include <hip/hip_runtime.h>

#define NN 50000
#define KSEQ 20
#define HN_OFF 6400000   // N*128
#define CN_OFF 12800000  // 2*N*128

using short8 = __attribute__((ext_vector_type(8))) short;
using f32x4  = __attribute__((ext_vector_type(4))) float;

__device__ __forceinline__ unsigned short f2bf(float f) {
    unsigned int u = __float_as_uint(f);
    return (unsigned short)((u + 0x7FFFu + ((u >> 16) & 1u)) >> 16);  // RNE
}
__device__ __forceinline__ float exp2x(float x) { float r; asm("v_exp_f32 %0, %1" : "=v"(r) : "v"(x)); return r; }
__device__ __forceinline__ float rcpx(float x)  { float r; asm("v_rcp_f32 %0, %1" : "=v"(r) : "v"(x)); return r; }

#define L2E 1.4426950408889634f
// inputs PRE-SCALED: sigmoid gets y = -l2e*x, tanh gets y = 2*l2e*x
__device__ __forceinline__ float sigp(float y)  { return rcpx(1.f + exp2x(y)); }
__device__ __forceinline__ float tanhp(float y) { return fmaf(-2.f, rcpx(1.f + exp2x(y)), 1.f); }

// ---- prep: bf16 weight packs (pre-scaled LSTM weights, transposes, bias sum) ----
__global__ void prep_kernel(const float* __restrict__ Wp, const float* __restrict__ W,
                            const float* __restrict__ Wih, const float* __restrict__ Whh,
                            const float* __restrict__ bih, const float* __restrict__ bhh,
                            unsigned short* __restrict__ Wih_b, unsigned short* __restrict__ Whh_b,
                            unsigned short* __restrict__ Wpt, unsigned short* __restrict__ Wtt,
                            float* __restrict__ bsum) {
    int tid = blockIdx.x * blockDim.x + threadIdx.x;
    if (tid < 65536) {  // gate scale: i,f,o -> -l2e ; g -> +2*l2e
        float sc = ((tid >> 14) == 2) ? (2.f * L2E) : (-L2E);
        Wih_b[tid] = f2bf(Wih[tid] * sc); return;
    }
    tid -= 65536;
    if (tid < 65536) {
        float sc = ((tid >> 14) == 2) ? (2.f * L2E) : (-L2E);
        Whh_b[tid] = f2bf(Whh[tid] * sc); return;
    }
    tid -= 65536;
    if (tid < 32768) { int j = tid >> 8, k = tid & 255; Wpt[tid] = f2bf(Wp[k * 128 + j]); return; }
    tid -= 32768;
    if (tid < 32768) { int j = tid >> 8, k = tid & 255; Wtt[tid] = f2bf(W[k * 128 + j]); return; }
    tid -= 32768;
    if (tid < 512) {
        float sc = ((tid >> 7) == 2) ? (2.f * L2E) : (-L2E);
        bsum[tid] = (bih[tid] + bhh[tid]) * sc;
    }
}

// ---- K1: hp = bf16(h @ W_past), 32 rows/block, 8 waves (16 cols each) ----
__global__ __launch_bounds__(512, 2) void hp_kernel(const float* __restrict__ h,
                                                    const unsigned short* __restrict__ Wpt,
                                                    unsigned short* __restrict__ hp_bf) {
    __shared__ __align__(16) unsigned char smem[32 * 512];
    const int tid = threadIdx.x;
    const int w = tid >> 6, l = tid & 63;
    const int l15 = l & 15, lq = l >> 4;
    const int base = blockIdx.x * 32;

#pragma unroll
    for (int i = 0; i < 4; ++i) {
        int chunk = tid + 512 * i;
        int row = chunk >> 6, kc = chunk & 63;
        int grow = base + row;
        float4 v = make_float4(0.f, 0.f, 0.f, 0.f);
        if (grow < NN) v = *(const float4*)(h + (size_t)grow * 256 + kc * 4);
        ushort4 bv = make_ushort4(f2bf(v.x), f2bf(v.y), f2bf(v.z), f2bf(v.w));
        int off = (row * 512 + kc * 8) ^ ((row & 7) << 4);
        *(ushort4*)(smem + off) = bv;
    }
    __syncthreads();

    const int jb = w * 16 + l15;
    short8 bf[8];
#pragma unroll
    for (int kt = 0; kt < 8; ++kt)
        bf[kt] = *(const short8*)((const unsigned char*)Wpt + jb * 512 + kt * 64 + lq * 16);

    f32x4 acc[2];
    acc[0] = (f32x4){0.f, 0.f, 0.f, 0.f};
    acc[1] = (f32x4){0.f, 0.f, 0.f, 0.f};
#pragma unroll
    for (int kt = 0; kt < 8; ++kt) {
#pragma unroll
        for (int rt = 0; rt < 2; ++rt) {
            int arow = rt * 16 + l15;
            int off = (arow * 512 + kt * 64 + lq * 16) ^ ((arow & 7) << 4);
            short8 a = *(const short8*)(smem + off);
            acc[rt] = __builtin_amdgcn_mfma_f32_16x16x32_bf16(a, bf[kt], acc[rt], 0, 0, 0);
        }
    }
#pragma unroll
    for (int rt = 0; rt < 2; ++rt)
#pragma unroll
        for (int r = 0; r < 4; ++r) {
            int row = rt * 16 + lq * 4 + r;
            int grow = base + row;
            if (grow < NN) hp_bf[(size_t)grow * 128 + w * 16 + l15] = f2bf(acc[rt][r]);
        }
}

// ---- K2: 16-wave split-gate LSTM, 32 rows/block, 4 waves/SIMD target.
// p0 waves (0-7): gates (i,g) for 16 cols; p1 waves (8-15): gates (f,o).
// Interval A(t): p0 gather-issue x(t+2) | h-GEMM(t) into acc | p0: a=sig(i)*tanh(g)->SB;
//                p1: cst*=sig(f), bf16(sig(o))->SB2
// Interval B(t): x-GEMM(t+1) into reborn acc | p1: c=cst+a, h->HB (+h_n/c_n at 19)
//                | p0: store staged x
// LDS (48KB): xbuf par0 @0, par1 @8192, hbuf @16384, a-slab @24576(16K), so-slab @40960(8K)
#define XP0 0
#define XP1 8192
#define HB  16384
#define SB  24576
#define SB2 40960

__device__ __forceinline__ void gemm8(const unsigned char* lds, int bufbase, int off0,
                                      const short8 (&bw)[2][8], int k0, f32x4 (&acc)[2][2]) {
#pragma unroll
    for (int kt = 0; kt < 4; ++kt) {
        const int o = bufbase + (off0 ^ (kt << 6));
#pragma unroll
        for (int rt = 0; rt < 2; ++rt) {
            short8 a = *(const short8*)(lds + rt * 4096 + o);
            acc[0][rt] = __builtin_amdgcn_mfma_f32_16x16x32_bf16(a, bw[0][k0 + kt], acc[0][rt], 0, 0, 0);
            acc[1][rt] = __builtin_amdgcn_mfma_f32_16x16x32_bf16(a, bw[1][k0 + kt], acc[1][rt], 0, 0, 0);
        }
    }
}

__global__ __launch_bounds__(1024, 4) void lstm_kernel(const unsigned short* __restrict__ hp_bf,
                                                       const int* __restrict__ agg,
                                                       const unsigned short* __restrict__ Wih_b,
                                                       const unsigned short* __restrict__ Whh_b,
                                                       const unsigned short* __restrict__ Wtt,
                                                       const float* __restrict__ bsum,
                                                       float* __restrict__ out) {
    __shared__ __align__(16) unsigned char lds[49152];
    const int tid = threadIdx.x;
    const int w = tid >> 6, l = tid & 63;
    const int p = w >> 3, b = w & 7;
    const int l15 = l & 15, lq = l >> 4;
    const int base = blockIdx.x * 32;
    const int colj = b * 16 + l15;

    // B frags: p0 -> (i @ row 0, g @ row 256); p1 -> (f @ 128, o @ 384)
    short8 bw[2][8];
    const int jA = p * 128 + colj;
#pragma unroll
    for (int kt = 0; kt < 4; ++kt) {
        bw[0][kt]     = *(const short8*)((const unsigned char*)Wih_b + jA * 256 + kt * 64 + lq * 16);
        bw[1][kt]     = *(const short8*)((const unsigned char*)Wih_b + (jA + 256) * 256 + kt * 64 + lq * 16);
        bw[0][kt + 4] = *(const short8*)((const unsigned char*)Whh_b + jA * 256 + kt * 64 + lq * 16);
        bw[1][kt + 4] = *(const short8*)((const unsigned char*)Whh_b + (jA + 256) * 256 + kt * 64 + lq * 16);
    }
    const float bi0 = bsum[jA];
    const float bi1 = bsum[jA + 256];

    // A-frag base (rt=0,kt=0); rt adds 4096; kt XORs kt<<6
    const int off0 = (l15 * 256 + lq * 16) ^ ((l15 & 7) << 4);
    // exchange slabs: flat per (rt,e,b,lane) -> 2-way max bank aliasing
    const int sb0 = SB + b * 256 + l * 4;       // fp32 a-values (+rt*8192 +e*2048)
    const int sb2 = SB2 + b * 128 + l * 2;      // bf16 sig(o)   (+rt*4096 +e*1024)
    // hbuf write base: row = rt*16 + lq*4 + e
    const int hb0 = lq * 1024 + colj * 2;

    // staging (p0 waves): lane covers (row srow, 16B chunk l15)
    const int srow = b * 4 + lq;
    const int grow_nom = base + srow;
    const int sgrow = grow_nom < NN ? grow_nom : NN - 1;
    const int* aggrow = agg + (size_t)sgrow * KSEQ;
    const int xw_off = (srow * 256 + l15 * 16) ^ ((srow & 7) << 4);
    const unsigned char* hp8 = (const unsigned char*)hp_bf;

    f32x4 cst[2];
    cst[0] = (f32x4){0.f, 0.f, 0.f, 0.f};
    cst[1] = (f32x4){0.f, 0.f, 0.f, 0.f};
    f32x4 acc[2][2];
    uint4 vnext;
    int gidx = 0;

    if (p == 0) {
        int i0 = aggrow[0], i1 = aggrow[1];
        uint4 v0 = *(const uint4*)(hp8 + (size_t)i0 * 256 + l15 * 16);
        uint4 v1 = *(const uint4*)(hp8 + (size_t)i1 * 256 + l15 * 16);
        *(uint4*)(lds + XP0 + xw_off) = v0;   // x_0
        *(uint4*)(lds + XP1 + xw_off) = v1;   // x_1
        gidx = aggrow[2];
    }
    __syncthreads();

    // prologue: acc = bias + x_0 @ Wx
    acc[0][0] = (f32x4){bi0, bi0, bi0, bi0}; acc[0][1] = acc[0][0];
    acc[1][0] = (f32x4){bi1, bi1, bi1, bi1}; acc[1][1] = acc[1][0];
    __builtin_amdgcn_s_setprio(1);
    gemm8(lds, XP0, off0, bw, 0, acc);
    __builtin_amdgcn_s_setprio(0);

#pragma unroll 1
    for (int t = 0; t < KSEQ; ++t) {
        // ---------------- interval A(t) ----------------
        if (p == 0 && t <= 18) {   // gather x_{t+2} (t=18: own hp row for epilogue)
            vnext = *(const uint4*)(hp8 + (size_t)gidx * 256 + l15 * 16);
            gidx = (t <= 16) ? aggrow[t + 3] : sgrow;
        }
        if (t > 0) {               // h-GEMM(t): acc += h_t @ Wh
            __builtin_amdgcn_s_setprio(1);
            gemm8(lds, HB, off0, bw, 4, acc);
            __builtin_amdgcn_s_setprio(0);
        }
        if (p == 0) {
#pragma unroll
            for (int rt = 0; rt < 2; ++rt)
#pragma unroll
                for (int e = 0; e < 4; ++e) {
                    float av = sigp(acc[0][rt][e]) * tanhp(acc[1][rt][e]);
                    *(float*)(lds + sb0 + rt * 8192 + e * 2048) = av;
                }
        } else {
#pragma unroll
            for (int rt = 0; rt < 2; ++rt)
#pragma unroll
                for (int e = 0; e < 4; ++e) {
                    cst[rt][e] *= sigp(acc[0][rt][e]);                   // fold sig(f)
                    *(unsigned short*)(lds + sb2 + rt * 4096 + e * 1024) = f2bf(sigp(acc[1][rt][e]));
                }
        }
        __syncthreads();  // a/so slabs visible; xbuf/hbuf MFMA reads done

        // ---------------- interval B(t) ----------------
        if (t < KSEQ - 1) {        // x-GEMM(t+1) into reborn acc
            acc[0][0] = (f32x4){bi0, bi0, bi0, bi0}; acc[0][1] = acc[0][0];
            acc[1][0] = (f32x4){bi1, bi1, bi1, bi1}; acc[1][1] = acc[1][0];
            __builtin_amdgcn_s_setprio(1);
            gemm8(lds, ((t + 1) & 1) ? XP1 : XP0, off0, bw, 0, acc);
            __builtin_amdgcn_s_setprio(0);
        }
        if (p == 1) {
#pragma unroll
            for (int rt = 0; rt < 2; ++rt)
#pragma unroll
                for (int e = 0; e < 4; ++e) {
                    float a = *(const float*)(lds + sb0 + rt * 8192 + e * 2048);
                    float c = cst[rt][e] + a;
                    cst[rt][e] = c;
                    unsigned short su = *(const unsigned short*)(lds + sb2 + rt * 4096 + e * 1024);
                    float so = __uint_as_float((unsigned)su << 16);
                    float hv = so * tanhp((2.f * L2E) * c);
                    unsigned pk;
                    asm("v_cvt_pk_bf16_f32 %0, %1, %2" : "=v"(pk) : "v"(hv), "v"(hv));
                    int row = rt * 16 + lq * 4 + e;
                    int hoff = (hb0 + rt * 4096 + e * 256) ^ ((row & 7) << 4);
                    *(unsigned short*)(lds + HB + hoff) = (unsigned short)pk;
                    if (t == KSEQ - 1) {
                        int grow = base + row;
                        if (grow < NN) {
                            out[HN_OFF + (size_t)grow * 128 + colj] = hv;
                            out[CN_OFF + (size_t)grow * 128 + colj] = c;
                        }
                    }
                }
        } else if (t <= 18) {
            *(uint4*)(lds + ((t & 1) ? XP1 : XP0) + xw_off) = vnext;  // x_{t+2} / own hp
        }
        __syncthreads();  // hbuf = h_{t+1}, staged x visible
    }
    // here: hbuf = h_20; xbuf par0 = own hp rows (staged at t=18)

    // epilogue: out = elu([hp | h_n] @ W); 16 waves: cols colj, row-half rt = p
    short8 bo[8];
#pragma unroll
    for (int kt = 0; kt < 8; ++kt)
        bo[kt] = *(const short8*)((const unsigned char*)Wtt + colj * 512 + kt * 64 + lq * 16);

    f32x4 a2 = (f32x4){0.f, 0.f, 0.f, 0.f};
    const int ebase = p * 4096;
#pragma unroll
    for (int kt = 0; kt < 4; ++kt) {
        short8 a = *(const short8*)(lds + XP0 + ebase + (off0 ^ (kt << 6)));  // hp
        a2 = __builtin_amdgcn_mfma_f32_16x16x32_bf16(a, bo[kt], a2, 0, 0, 0);
    }
#pragma unroll
    for (int kt = 0; kt < 4; ++kt) {
        short8 a = *(const short8*)(lds + HB + ebase + (off0 ^ (kt << 6)));   // h_n
        a2 = __builtin_amdgcn_mfma_f32_16x16x32_bf16(a, bo[kt + 4], a2, 0, 0, 0);
    }
#pragma unroll
    for (int e = 0; e < 4; ++e) {
        int grow = base + p * 16 + lq * 4 + e;
        if (grow < NN) {
            float v = a2[e];
            out[(size_t)grow * 128 + colj] = (v > 0.f) ? v : (exp2x(L2E * v) - 1.f);
        }
    }
}

extern "C" void kernel_launch(void* const* d_in, const int* in_sizes, int n_in,
                              void* d_out, int out_size, void* d_ws, size_t ws_size,
                              hipStream_t stream) {
    (void)in_sizes; (void)n_in; (void)out_size; (void)ws_size;
    const float* h   = (const float*)d_in[0];
    const int*   agg = (const int*)d_in[1];
    const float* Wp  = (const float*)d_in[2];
    const float* W   = (const float*)d_in[3];
    const float* Wih = (const float*)d_in[4];
    const float* Whh = (const float*)d_in[5];
    const float* bih = (const float*)d_in[6];
    const float* bhh = (const float*)d_in[7];
    float* out = (float*)d_out;

    unsigned short* hp_bf = (unsigned short*)d_ws;       // 50000*128 bf16
    unsigned short* Wih_b = hp_bf + 6400000;             // 512*128 (pre-scaled)
    unsigned short* Whh_b = Wih_b + 65536;               // 512*128 (pre-scaled)
    unsigned short* Wpt   = Whh_b + 65536;               // 128*256 (W_past^T)
    unsigned short* Wtt   = Wpt + 32768;                 // 128*256 (W^T)
    float*          bsum  = (float*)(Wtt + 32768);       // 512 (pre-scaled)

    prep_kernel<<<771, 256, 0, stream>>>(Wp, W, Wih, Whh, bih, bhh, Wih_b, Whh_b, Wpt, Wtt, bsum);
    hp_kernel<<<1563, 512, 0, stream>>>(h, Wpt, hp_bf);
    lstm_kernel<<<1563, 1024, 0, stream>>>(hp_bf, agg, Wih_b, Whh_b, Wtt, bsum, out);
}